// Round 2
// baseline (537.915 us; speedup 1.0000x reference)
//
#include <hip/hip_runtime.h>

// GenLSTM: B=8192, T=256 (255 steps), noise=8, seq_dim=4, HID=64, gates=256.
// R7: dual-chain block. R6 post-mortem: single-barrier needed per-wave copies of
// the whole MLP -> 200 VGPR demand vs 128 allocated -> scratch (WRITE_SIZE +19MB,
// FETCH +9.5MB) and +54% bank conflicts => 469us. Lesson: don't trade barriers
// for register residency. R7 reverts to R5's 96-VGPR wave-split weights and
// instead processes TWO independent 16-row batch groups per block (M=32, 256
// blocks, 4 waves, ~1 block/CU): every phase runs group A then group B in the
// same wave, so the 3 barriers serve 2 group-steps (1.5 barriers/group-step) and
// each group's LDS latency is hidden by the other group's MFMA/VALU in program
// order instead of by scheduler luck across blocks. Weights are SHARED between
// groups (+~40 VGPRs of state only). Kept from R6 (register-free): gate bias
// folded into a constant-1 row of a2 staging (u[76]=1, weight row = b[n]) ->
// z accumulators re-init to 0, bzv regs gone. Kept from R5: swapped-operand
// MFMA (weights=A -> C^T), 7-trans cell with inf-safe clamps, redundant x-phase,
// wave-private a2 staging, pipelined gate-h MFMAs reusing the y1-phase h frags.

typedef _Float16 h8 __attribute__((ext_vector_type(8)));
typedef __fp16 p2h __attribute__((ext_vector_type(2)));
typedef float f4 __attribute__((ext_vector_type(4)));

#define MFMA(a, b, c) __builtin_amdgcn_mfma_f32_16x16x32_f16(a, b, c, 0, 0, 0)

constexpr int SEQ = 256, STEPS = 255, ND = 8, SD = 4, HID = 64, G4 = 256;
constexpr int HST  = 72;  // h/y row stride (f16): 16B-aligned rows
constexpr int A2ST = 24;  // wave-private a2 staging row stride

__device__ __forceinline__ void store4h(_Float16* p, f4 v) {
    p2h lo = __builtin_amdgcn_cvt_pkrtz(v[0], v[1]);
    p2h hi = __builtin_amdgcn_cvt_pkrtz(v[2], v[3]);
    float2 st;
    st.x = __builtin_bit_cast(float, lo);
    st.y = __builtin_bit_cast(float, hi);
    *(float2*)p = st;
}
__device__ __forceinline__ void store2h(_Float16* p, float a, float b_) {
    p2h v = __builtin_amdgcn_cvt_pkrtz(a, b_);
    *(float*)p = __builtin_bit_cast(float, v);
}

__global__ __launch_bounds__(256, 1) void genlstm_kernel(
    const float* __restrict__ noise, const float* __restrict__ Wx,
    const float* __restrict__ Wh, const float* __restrict__ b,
    const float* __restrict__ W1, const float* __restrict__ b1,
    const float* __restrict__ W2, const float* __restrict__ b2,
    const float* __restrict__ W3, const float* __restrict__ b3,
    float* __restrict__ out)
{
    // per-group LDS panels (g = 0,1 -> batch rows row0+16g .. +15)
    __shared__ alignas(16) _Float16 Hb[2][2 * 16 * HST];   // [g][pb][row][HST]
    __shared__ alignas(16) _Float16 Y1b[2][16 * HST];
    __shared__ alignas(16) _Float16 Y2b[2][16 * HST];
    __shared__ alignas(16) _Float16 A2b[2][4 * 16 * A2ST]; // [g][wid][row][A2ST]
    __shared__ alignas(16) _Float16 Zb[8];                 // zeros (a2 quads 2/3)

    const int tid = threadIdx.x, wid = tid >> 6, lane = tid & 63;
    const int col = lane & 15, quad = lane >> 4, q8 = quad * 8;
    const int row0 = blockIdx.x * 32;
    const int n0 = wid * 16 + col;       // gate/hid col for weight frags
    const int wq = wid * 16 + quad * 4;  // C^T write col base

    // ---- gate weight frags (column-split across waves, bias folded) ----
    // u index k: [0..63]=h, [64..67]=x, [68..75]=noise, [76]=1 (bias), [77..95]=0
    h8 wg[4][3];
    #pragma unroll
    for (int g = 0; g < 4; ++g)
        #pragma unroll
        for (int s = 0; s < 3; ++s)
            #pragma unroll
            for (int j = 0; j < 8; ++j) {
                const int k = 32 * s + q8 + j;
                const int n = 64 * g + n0;
                float v;
                if (k < 64) v = Wh[k * G4 + n];
                else if (k < 76) v = Wx[(k - 64) * G4 + n];
                else if (k == 76) v = b[n];
                else v = 0.0f;
                wg[g][s][j] = (_Float16)v;
            }
    // ---- MLP weight frags (wave-split, 16 cols each -- R5 layout) ----
    h8 w1f[2], w2f[2], w3f[2];
    #pragma unroll
    for (int s = 0; s < 2; ++s)
        #pragma unroll
        for (int j = 0; j < 8; ++j) {
            const int k = 32 * s + q8 + j;
            w1f[s][j] = (_Float16)W1[k * HID + n0];
            w2f[s][j] = (_Float16)W2[k * HID + n0];
            w3f[s][j] = (_Float16)(col < 4 ? W3[k * SD + col] : 0.0f);
        }
    // biases by OUTPUT index (C^T): n = wq + r
    f4 b1v, b2v, b3v;
    #pragma unroll
    for (int r = 0; r < 4; ++r) {
        b1v[r] = b1[wq + r];
        b2v[r] = b2[wq + r];
        b3v[r] = (quad == 0) ? b3[r] : 0.0f;
    }

    // ---- LDS init (a2: zeros except the constant bias-1 at elem 12 = k 76) ----
    for (int i = tid; i < 2 * 2 * 16 * HST; i += 256) (&Hb[0][0])[i] = (_Float16)0;
    for (int i = tid; i < 2 * 4 * 16 * A2ST; i += 256)
        (&A2b[0][0])[i] = (i % A2ST == 12) ? (_Float16)1 : (_Float16)0;
    if (tid < 8) Zb[tid] = (_Float16)0;
    if (tid < 32) {  // out[:,0,:] = 0
        float4 z; z.x = z.y = z.z = z.w = 0.0f;
        *(float4*)(out + (size_t)(row0 + tid) * SEQ * SD) = z;
    }
    __syncthreads();

    // ---- loop-invariant pointers, per group ----
    const int nrow = lane >> 2, ncc = (lane & 3) * 2;
    const float* nptr[2];
    _Float16* a2n_[2];
    _Float16* a2x_[2];
    const _Float16* a2rd_[2];
    _Float16* Y1r_[2];
    _Float16* Y2r_[2];
    float* outp_[2];
    #pragma unroll
    for (int g = 0; g < 2; ++g) {
        nptr[g]  = noise + ((size_t)(row0 + 16 * g + nrow) * SEQ) * ND + ncc;
        a2n_[g]  = &A2b[g][(wid * 16 + nrow) * A2ST + 4 + ncc];
        a2x_[g]  = &A2b[g][(wid * 16 + col) * A2ST];
        a2rd_[g] = (quad < 2) ? &A2b[g][(wid * 16 + col) * A2ST + 8 * quad] : Zb;
        Y1r_[g]  = &Y1b[g][col * HST];
        Y2r_[g]  = &Y2b[g][col * HST];
        outp_[g] = out + ((size_t)(row0 + 16 * g + col) * SEQ + 1) * SD;
    }

    // stage noise(0); x(0)=0 from zero-init (wave-private, no barrier)
    #pragma unroll
    for (int g = 0; g < 2; ++g) {
        float2 nz = *(const float2*)nptr[g];
        store2h(a2n_[g], nz.x, nz.y);
        nptr[g] += ND;
    }

    const f4 fz = {0.f, 0.f, 0.f, 0.f};
    f4 cst[2] = {fz, fz}, run[2] = {fz, fz};
    // z accumulators persist across iterations; bias arrives via the u[76]=1
    // row in the a2 staging, so init is plain zero (h(0)=0).
    f4 zi[2] = {fz, fz}, zf[2] = {fz, fz}, zg[2] = {fz, fz}, zo[2] = {fz, fz};
    h8 h0[2], h1[2];  // h(t+1) frags, loaded post-B1, reused for gate-h MFMAs

    auto body = [&](int pb) {
        // ---- complete z(t): a2 slice (x|noise|1), both groups ----
        float2 nz[2];
        #pragma unroll
        for (int g = 0; g < 2; ++g) {
            nz[g] = *(const float2*)nptr[g];   // prefetch noise(t+1), in-bounds
            nptr[g] += ND;
            h8 a2 = *(const h8*)a2rd_[g];
            zi[g] = MFMA(wg[0][2], a2, zi[g]);
            zf[g] = MFMA(wg[1][2], a2, zf[g]);
            zg[g] = MFMA(wg[2][2], a2, zg[g]);
            zo[g] = MFMA(wg[3][2], a2, zo[g]);
        }

        // ---- cell update x2, 7 transcendentals each (shared denom, clamps) ----
        #pragma unroll
        for (int g = 0; g < 2; ++g) {
            f4 hv;
            #pragma unroll
            for (int r = 0; r < 4; ++r) {
                float Ei = __expf(-fmaxf(zi[g][r], -15.f));
                float Ef = __expf(-fmaxf(zf[g][r], -15.f));
                float Eg = __expf(-2.f * fmaxf(zg[g][r], -15.f));
                float Eo = __expf(-zo[g][r]);
                float Di = 1.f + Ei, Df = 1.f + Ef, Dg = 1.f + Eg, Do = 1.f + Eo;
                float DiDg = Di * Dg;
                float cn = (cst[g][r] * DiDg + (2.f - Dg) * Df) *
                           __builtin_amdgcn_rcpf(Df * DiDg);
                cst[g][r] = cn;
                float Ec = __expf(-2.f * fmaxf(cn, -15.f));
                hv[r] = (1.f - Ec) * __builtin_amdgcn_rcpf(Do * (1.f + Ec));
            }
            store4h(&Hb[g][((pb ^ 1) * 16 + col) * HST] + wq, hv);  // h(t+1)
        }
        __syncthreads();  // B1

        // ---- y1 = relu(h(t+1) @ W1 + b1), both groups ----
        #pragma unroll
        for (int g = 0; g < 2; ++g) {
            const _Float16* hb = &Hb[g][((pb ^ 1) * 16 + col) * HST];
            h0[g] = *(const h8*)(hb + q8);
            h1[g] = *(const h8*)(hb + 32 + q8);
            f4 y1 = b1v;
            y1 = MFMA(w1f[0], h0[g], y1);
            y1 = MFMA(w1f[1], h1[g], y1);
            #pragma unroll
            for (int r = 0; r < 4; ++r) y1[r] = fmaxf(y1[r], 0.0f);
            store4h(Y1r_[g] + wq, y1);
        }

        // ---- software-pipelined gate-h MFMAs for t+1 (h0/h1 reused; they
        //      overlap the y1 write->read LDS latency of both groups) ----
        #pragma unroll
        for (int g = 0; g < 2; ++g) {
            zi[g] = fz; zi[g] = MFMA(wg[0][0], h0[g], zi[g]); zi[g] = MFMA(wg[0][1], h1[g], zi[g]);
            zf[g] = fz; zf[g] = MFMA(wg[1][0], h0[g], zf[g]); zf[g] = MFMA(wg[1][1], h1[g], zf[g]);
            zg[g] = fz; zg[g] = MFMA(wg[2][0], h0[g], zg[g]); zg[g] = MFMA(wg[2][1], h1[g], zg[g]);
            zo[g] = fz; zo[g] = MFMA(wg[3][0], h0[g], zo[g]); zo[g] = MFMA(wg[3][1], h1[g], zo[g]);
        }
        __syncthreads();  // B2

        // ---- y2 = relu(y1 @ W2 + b2), both groups ----
        #pragma unroll
        for (int g = 0; g < 2; ++g) {
            h8 p0 = *(const h8*)(Y1r_[g] + q8);
            h8 p1 = *(const h8*)(Y1r_[g] + 32 + q8);
            f4 y2 = b2v;
            y2 = MFMA(w2f[0], p0, y2);
            y2 = MFMA(w2f[1], p1, y2);
            #pragma unroll
            for (int r = 0; r < 4; ++r) y2[r] = fmaxf(y2[r], 0.0f);
            store4h(Y2r_[g] + wq, y2);
        }
        __syncthreads();  // B3

        // ---- x = y2 @ W3 + b3 (all waves redundantly; quad0 = real cols) ----
        #pragma unroll
        for (int g = 0; g < 2; ++g) {
            h8 q0 = *(const h8*)(Y2r_[g] + q8);
            h8 q1 = *(const h8*)(Y2r_[g] + 32 + q8);
            f4 x = b3v;
            x = MFMA(w3f[0], q0, x);
            x = MFMA(w3f[1], q1, x);

            if (quad == 0) {
                store4h(a2x_[g], x);         // x(t+1) into own a2 staging
                if (wid == 0) {
                    run[g] += x;
                    *(f4*)outp_[g] = run[g]; // cumsum output, dwordx4
                }
            }
            store2h(a2n_[g], nz[g].x, nz[g].y);  // noise(t+1) into a2 staging
            outp_[g] += SD;
        }
    };

    #pragma unroll 1
    for (int t = 0; t < STEPS - 1; t += 2) {
        body(0);
        body(1);
    }
    body(0);  // t = 254
}

extern "C" void kernel_launch(void* const* d_in, const int* in_sizes, int n_in,
                              void* d_out, int out_size, void* d_ws, size_t ws_size,
                              hipStream_t stream) {
    genlstm_kernel<<<256, 256, 0, stream>>>(
        (const float*)d_in[0], (const float*)d_in[1], (const float*)d_in[2],
        (const float*)d_in[3], (const float*)d_in[4], (const float*)d_in[5],
        (const float*)d_in[6], (const float*)d_in[7], (const float*)d_in[8],
        (const float*)d_in[9], (float*)d_out);
}

// Round 4
// 436.711 us; speedup vs baseline: 1.2317x; 1.2317x over previous
//
#include <hip/hip_runtime.h>

// GenLSTM: B=8192, T=256 (255 steps), noise=8, seq_dim=4, HID=64, gates=256.
// R9 = R8 with the exp2 intrinsic spelled correctly for hipcc
// (__builtin_amdgcn_exp2f, maps to v_exp_f32; __exp2f is CUDA-only).
// R8 design: R5 skeleton (512 blocks x 4 waves, M=16, 3 barriers, 2 blocks/CU)
// with the recurrence critical path shortened:
// (1) W3W fold: x@Wx_x == y2@(W3@Wx_x) + b3@Wx_x, so gates consume the y2 frags
//     directly after B3 (z += y2@W3W, 8 MFMAs) -- the x->pack->ds_write->ds_read
//     round trip is OFF the serial chain. x is computed only by wave 0, only for
//     the cumsum output.
// (2) a2 LDS staging deleted: noise enters as a register-built B-frag (quad0
//     lanes load noise[b][t][0..8) as 2x dwordx4, prefetched one full step
//     ahead); bias rides as MFMA C-init frags (bzv), not LDS rows.
// (3) exp2 prescale: gate weights/biases scaled by log2e (g-gate by 2*log2e) so
//     the cell uses v_exp_f32 directly; clamps rescaled to match R5 exactly.
// (4) biases as C-initializers for the first MFMA of each chain (no v_mov init).
// LDS 6.9 KB (Hb single-buffered: h reads finish before B2, next write after B3).

typedef _Float16 h8 __attribute__((ext_vector_type(8)));
typedef __fp16 p2h __attribute__((ext_vector_type(2)));
typedef float f4 __attribute__((ext_vector_type(4)));

#define MFMA(a, b, c) __builtin_amdgcn_mfma_f32_16x16x32_f16(a, b, c, 0, 0, 0)
#define EXP2(x) __builtin_amdgcn_exp2f(x)

constexpr int SEQ = 256, STEPS = 255, ND = 8, SD = 4, HID = 64, G4 = 256;
constexpr int HST = 72;  // h/y row stride (f16): 16B-aligned rows
constexpr float LOG2E = 1.44269504f;

__device__ __forceinline__ void store4h(_Float16* p, f4 v) {
    p2h lo = __builtin_amdgcn_cvt_pkrtz(v[0], v[1]);
    p2h hi = __builtin_amdgcn_cvt_pkrtz(v[2], v[3]);
    float2 st;
    st.x = __builtin_bit_cast(float, lo);
    st.y = __builtin_bit_cast(float, hi);
    *(float2*)p = st;
}

__global__ __launch_bounds__(256, 2) void genlstm_kernel(
    const float* __restrict__ noise, const float* __restrict__ Wx,
    const float* __restrict__ Wh, const float* __restrict__ b,
    const float* __restrict__ W1, const float* __restrict__ b1,
    const float* __restrict__ W2, const float* __restrict__ b2,
    const float* __restrict__ W3, const float* __restrict__ b3,
    float* __restrict__ out)
{
    __shared__ alignas(16) _Float16 Hb[16 * HST];
    __shared__ alignas(16) _Float16 Y1b[16 * HST];
    __shared__ alignas(16) _Float16 Y2b[16 * HST];

    const int tid = threadIdx.x, wid = tid >> 6, lane = tid & 63;
    const int col = lane & 15, quad = lane >> 4, q8 = quad * 8;
    const int row0 = blockIdx.x * 16;
    const int n0 = wid * 16 + col;       // gate/hid col for weight frags
    const int wq = wid * 16 + quad * 4;  // C^T write col base

    const float gsc[4] = {LOG2E, LOG2E, 2.f * LOG2E, LOG2E};  // i,f,g,o

    // ---- gate weight frags (column-split across waves, exp2-prescaled) ----
    // wg[g][0..1]: Wh k-slices (k=0..63). wg[g][2]: noise slice, k=0..7 live
    // (quad0 lanes), rest 0.
    h8 wg[4][3];
    #pragma unroll
    for (int g = 0; g < 4; ++g)
        #pragma unroll
        for (int s = 0; s < 3; ++s)
            #pragma unroll
            for (int j = 0; j < 8; ++j) {
                const int n = 64 * g + n0;
                float v;
                if (s < 2) v = Wh[(32 * s + q8 + j) * G4 + n];
                else       v = (q8 + j < 8) ? Wx[(4 + q8 + j) * G4 + n] : 0.0f;
                wg[g][s][j] = (_Float16)(v * gsc[g]);
            }
    // ---- W3W = W3 @ Wx[0:4,:] fold (prescaled): z += y2 @ W3W ----
    h8 wgy[4][2];
    #pragma unroll
    for (int s = 0; s < 2; ++s)
        #pragma unroll
        for (int j = 0; j < 8; ++j) {
            const int k = 32 * s + q8 + j;
            const float w30 = W3[k * SD + 0], w31 = W3[k * SD + 1];
            const float w32 = W3[k * SD + 2], w33 = W3[k * SD + 3];
            #pragma unroll
            for (int g = 0; g < 4; ++g) {
                const int n = 64 * g + n0;
                float acc = w30 * Wx[0 * G4 + n] + w31 * Wx[1 * G4 + n] +
                            w32 * Wx[2 * G4 + n] + w33 * Wx[3 * G4 + n];
                wgy[g][s][j] = (_Float16)(acc * gsc[g]);
            }
        }
    // ---- MLP weight frags (wave-split, 16 cols each) ----
    h8 w1f[2], w2f[2], w3f[2];
    #pragma unroll
    for (int s = 0; s < 2; ++s)
        #pragma unroll
        for (int j = 0; j < 8; ++j) {
            const int k = 32 * s + q8 + j;
            w1f[s][j] = (_Float16)W1[k * HID + n0];
            w2f[s][j] = (_Float16)W2[k * HID + n0];
            w3f[s][j] = (_Float16)(col < 4 ? W3[k * SD + col] : 0.0f);
        }
    // ---- bias C-init frags (output index n = 64g + wq + r) ----
    // bzv: full recurrent bias b' = (b + b3 @ Wx_x) * gs  (steps >= 1)
    // bz0: plain b * gs (prologue only; x(0)=0 so no b3 contribution)
    f4 bzv[4], bz0[4], b1v, b2v, b3v;
    #pragma unroll
    for (int r = 0; r < 4; ++r) {
        #pragma unroll
        for (int g = 0; g < 4; ++g) {
            const int n = 64 * g + wq + r;
            float bx = b3[0] * Wx[0 * G4 + n] + b3[1] * Wx[1 * G4 + n] +
                       b3[2] * Wx[2 * G4 + n] + b3[3] * Wx[3 * G4 + n];
            bz0[g][r] = b[n] * gsc[g];
            bzv[g][r] = (b[n] + bx) * gsc[g];
        }
        b1v[r] = b1[wq + r];
        b2v[r] = b2[wq + r];
        b3v[r] = (quad == 0) ? b3[r] : 0.0f;
    }

    if (tid < 16) {  // out[:,0,:] = 0
        float4 z; z.x = z.y = z.z = z.w = 0.0f;
        *(float4*)(out + (size_t)(row0 + tid) * SEQ * SD) = z;
    }

    _Float16* Hrow = &Hb[col * HST];
    _Float16* Y1row = &Y1b[col * HST];
    _Float16* Y2row = &Y2b[col * HST];
    float* outp = out + ((size_t)(row0 + col) * SEQ + 1) * SD;

    // noise pointer: quad0 lanes own all 8 dims of batch row (row0+col)
    const float* npt = noise + (size_t)(row0 + col) * SEQ * ND;
    const float4 fz4 = {0.f, 0.f, 0.f, 0.f};
    const f4 fz = {0.f, 0.f, 0.f, 0.f};

    f4 cst = fz, run = fz;
    f4 zi, zf, zg, zo;

    // ---- prologue: z(0) = noise(0) @ Wxn + b   (h(0)=0, x(0)=0) ----
    {
        float4 nf0 = fz4, nf1 = fz4;
        if (quad == 0) { nf0 = *(const float4*)npt; nf1 = *(const float4*)(npt + 4); }
        npt += ND;
        union { h8 v; p2h p[4]; } nb;
        nb.p[0] = __builtin_amdgcn_cvt_pkrtz(nf0.x, nf0.y);
        nb.p[1] = __builtin_amdgcn_cvt_pkrtz(nf0.z, nf0.w);
        nb.p[2] = __builtin_amdgcn_cvt_pkrtz(nf1.x, nf1.y);
        nb.p[3] = __builtin_amdgcn_cvt_pkrtz(nf1.z, nf1.w);
        zi = MFMA(wg[0][2], nb.v, bz0[0]);
        zf = MFMA(wg[1][2], nb.v, bz0[1]);
        zg = MFMA(wg[2][2], nb.v, bz0[2]);
        zo = MFMA(wg[3][2], nb.v, bz0[3]);
    }

    #pragma unroll 1
    for (int t = 0; t < STEPS; ++t) {
        // prefetch noise(t+1) -- consumed at the tail, a full step of latency
        float4 nf0 = fz4, nf1 = fz4;
        if (quad == 0) { nf0 = *(const float4*)npt; nf1 = *(const float4*)(npt + 4); }
        npt += ND;

        // ---- cell update from complete z(t); 7 trans, exp2-prescaled ----
        f4 hv;
        #pragma unroll
        for (int r = 0; r < 4; ++r) {
            float Ei = EXP2(-fmaxf(zi[r], -15.f * LOG2E));
            float Ef = EXP2(-fmaxf(zf[r], -15.f * LOG2E));
            float Eg = EXP2(-fmaxf(zg[r], -30.f * LOG2E));
            float Eo = EXP2(-zo[r]);
            float Di = 1.f + Ei, Df = 1.f + Ef, Dg = 1.f + Eg, Do = 1.f + Eo;
            float DiDg = Di * Dg;
            float cn = (cst[r] * DiDg + (2.f - Dg) * Df) *
                       __builtin_amdgcn_rcpf(Df * DiDg);
            cst[r] = cn;
            float Ec = EXP2(fmaxf(cn, -15.f) * (-2.f * LOG2E));
            hv[r] = (1.f - Ec) * __builtin_amdgcn_rcpf(Do * (1.f + Ec));
        }
        store4h(Hrow + wq, hv);  // h(t+1)
        __syncthreads();  // B1

        h8 h0 = *(const h8*)(&Hb[col * HST] + q8);
        h8 h1 = *(const h8*)(&Hb[col * HST] + 32 + q8);

        // ---- y1 = relu(h @ W1 + b1) ----
        f4 y1 = MFMA(w1f[0], h0, b1v);
        y1 = MFMA(w1f[1], h1, y1);
        #pragma unroll
        for (int r = 0; r < 4; ++r) y1[r] = fmaxf(y1[r], 0.f);
        store4h(Y1row + wq, y1);

        // pipelined gate-h for z(t+1); bias arrives as C-init (no movs)
        zi = MFMA(wg[0][0], h0, bzv[0]); zi = MFMA(wg[0][1], h1, zi);
        zf = MFMA(wg[1][0], h0, bzv[1]); zf = MFMA(wg[1][1], h1, zf);
        zg = MFMA(wg[2][0], h0, bzv[2]); zg = MFMA(wg[2][1], h1, zg);
        zo = MFMA(wg[3][0], h0, bzv[3]); zo = MFMA(wg[3][1], h1, zo);
        __syncthreads();  // B2

        // ---- y2 = relu(y1 @ W2 + b2) ----
        h8 p0 = *(const h8*)(Y1row + q8);
        h8 p1 = *(const h8*)(Y1row + 32 + q8);
        f4 y2 = MFMA(w2f[0], p0, b2v);
        y2 = MFMA(w2f[1], p1, y2);
        #pragma unroll
        for (int r = 0; r < 4; ++r) y2[r] = fmaxf(y2[r], 0.f);
        store4h(Y2row + wq, y2);
        __syncthreads();  // B3

        h8 q0 = *(const h8*)(Y2row + q8);
        h8 q1 = *(const h8*)(Y2row + 32 + q8);

        // ---- z(t+1) += y2 @ W3W  (the folded x-contribution, on-path) ----
        zi = MFMA(wgy[0][0], q0, zi); zi = MFMA(wgy[0][1], q1, zi);
        zf = MFMA(wgy[1][0], q0, zf); zf = MFMA(wgy[1][1], q1, zf);
        zg = MFMA(wgy[2][0], q0, zg); zg = MFMA(wgy[2][1], q1, zg);
        zo = MFMA(wgy[3][0], q0, zo); zo = MFMA(wgy[3][1], q1, zo);

        // ---- z(t+1) += noise(t+1) @ Wxn  (prefetched; off-path) ----
        union { h8 v; p2h p[4]; } nb;
        nb.p[0] = __builtin_amdgcn_cvt_pkrtz(nf0.x, nf0.y);
        nb.p[1] = __builtin_amdgcn_cvt_pkrtz(nf0.z, nf0.w);
        nb.p[2] = __builtin_amdgcn_cvt_pkrtz(nf1.x, nf1.y);
        nb.p[3] = __builtin_amdgcn_cvt_pkrtz(nf1.z, nf1.w);
        zi = MFMA(wg[0][2], nb.v, zi);
        zf = MFMA(wg[1][2], nb.v, zf);
        zg = MFMA(wg[2][2], nb.v, zg);
        zo = MFMA(wg[3][2], nb.v, zo);

        // ---- x(t+1) = y2 @ W3 + b3: output only, wave 0 only, off-path ----
        if (wid == 0) {
            f4 x = MFMA(w3f[0], q0, b3v);
            x = MFMA(w3f[1], q1, x);
            if (quad == 0) {
                run += x;
                *(f4*)outp = run;  // cumsum output, dwordx4
            }
        }
        outp += SD;
    }
}

extern "C" void kernel_launch(void* const* d_in, const int* in_sizes, int n_in,
                              void* d_out, int out_size, void* d_ws, size_t ws_size,
                              hipStream_t stream) {
    genlstm_kernel<<<512, 256, 0, stream>>>(
        (const float*)d_in[0], (const float*)d_in[1], (const float*)d_in[2],
        (const float*)d_in[3], (const float*)d_in[4], (const float*)d_in[5],
        (const float*)d_in[6], (const float*)d_in[7], (const float*)d_in[8],
        (const float*)d_in[9], (float*)d_out);
}

// Round 5
// 399.115 us; speedup vs baseline: 1.3478x; 1.0942x over previous
//
#include <hip/hip_runtime.h>

// GenLSTM: B=8192, T=256 (255 steps), noise=8, seq_dim=4, HID=64, gates=256.
// R10 = R9's W3W-fold structure with the register demand cut to fit the
// allocator's empirical 128-VGPR ceiling (R5=96 clean; R6/R9=128+scratch:
// WRITE_SIZE 76MB vs 33.5MB output). Cuts vs R9 (~-28 regs):
// (1) bzv deleted: recurrent bias b' = (b + b3@Wx_x)*gsc folded into ROW k=8 of
//     the noise A-frag wgn -- that row occupies quad-1 lanes' frag slots that
//     were already zero (0 extra regs). B-frag carries 1.0 at k=8 via quad-1's
//     nf0.x, set ONCE outside the loop (quad0 is the only quad that reloads nf).
// (2) bz0 deleted: prologue bias C-init b*gsc from transient global loads
//     (dead after prologue; prologue B-frag has bias slot = 0 since x(0)=0).
// (3) gate-h MFMAs C-init from one shared zero f4 (D may differ from C).
// (4) nf lives outside the loop: quads 1-3 never re-zero it.
// Kept: R5 skeleton (512 blocks x 4 waves, M=16, 3 barriers, 2 blocks/CU),
// W3W fold (z += y2@W3W after B3; x-output off-path, wave0 only), register
// noise B-frag prefetched a full step, exp2-prescaled gates, 7-trans cell.

typedef _Float16 h8 __attribute__((ext_vector_type(8)));
typedef __fp16 p2h __attribute__((ext_vector_type(2)));
typedef float f4 __attribute__((ext_vector_type(4)));

#define MFMA(a, b, c) __builtin_amdgcn_mfma_f32_16x16x32_f16(a, b, c, 0, 0, 0)
#define EXP2(x) __builtin_amdgcn_exp2f(x)

constexpr int SEQ = 256, STEPS = 255, ND = 8, SD = 4, HID = 64, G4 = 256;
constexpr int HST = 72;  // h/y row stride (f16): 16B-aligned rows
constexpr float LOG2E = 1.44269504f;

__device__ __forceinline__ void store4h(_Float16* p, f4 v) {
    p2h lo = __builtin_amdgcn_cvt_pkrtz(v[0], v[1]);
    p2h hi = __builtin_amdgcn_cvt_pkrtz(v[2], v[3]);
    float2 st;
    st.x = __builtin_bit_cast(float, lo);
    st.y = __builtin_bit_cast(float, hi);
    *(float2*)p = st;
}

__global__ __launch_bounds__(256, 2) void genlstm_kernel(
    const float* __restrict__ noise, const float* __restrict__ Wx,
    const float* __restrict__ Wh, const float* __restrict__ b,
    const float* __restrict__ W1, const float* __restrict__ b1,
    const float* __restrict__ W2, const float* __restrict__ b2,
    const float* __restrict__ W3, const float* __restrict__ b3,
    float* __restrict__ out)
{
    __shared__ alignas(16) _Float16 Hb[16 * HST];
    __shared__ alignas(16) _Float16 Y1b[16 * HST];
    __shared__ alignas(16) _Float16 Y2b[16 * HST];

    const int tid = threadIdx.x, wid = tid >> 6, lane = tid & 63;
    const int col = lane & 15, quad = lane >> 4, q8 = quad * 8;
    const int row0 = blockIdx.x * 16;
    const int n0 = wid * 16 + col;       // gate/hid col for weight frags
    const int wq = wid * 16 + quad * 4;  // C^T write col base

    const float gsc[4] = {LOG2E, LOG2E, 2.f * LOG2E, LOG2E};  // i,f,g,o

    // ---- gate weight frags: Wh slices (k=0..63), exp2-prescaled ----
    h8 wg[4][2];
    #pragma unroll
    for (int g = 0; g < 4; ++g)
        #pragma unroll
        for (int s = 0; s < 2; ++s)
            #pragma unroll
            for (int j = 0; j < 8; ++j)
                wg[g][s][j] = (_Float16)(Wh[(32 * s + q8 + j) * G4 + 64 * g + n0] * gsc[g]);

    // ---- noise+bias slice: k=0..7 -> Wxn rows (quad0), k=8 -> b' row (quad1 j=0) ----
    // b' = b + b3 @ Wx_x  (the x-fold bias), prescaled.
    h8 wgn[4];
    #pragma unroll
    for (int g = 0; g < 4; ++g)
        #pragma unroll
        for (int j = 0; j < 8; ++j) {
            const int k = q8 + j;
            const int n = 64 * g + n0;
            float v = 0.0f;
            if (k < 8) v = Wx[(4 + k) * G4 + n];
            else if (k == 8) {
                float bx = b3[0] * Wx[0 * G4 + n] + b3[1] * Wx[1 * G4 + n] +
                           b3[2] * Wx[2 * G4 + n] + b3[3] * Wx[3 * G4 + n];
                v = b[n] + bx;
            }
            wgn[g][j] = (_Float16)(v * gsc[g]);
        }

    // ---- W3W = W3 @ Wx[0:4,:] fold (prescaled): z += y2 @ W3W ----
    h8 wgy[4][2];
    #pragma unroll
    for (int s = 0; s < 2; ++s)
        #pragma unroll
        for (int j = 0; j < 8; ++j) {
            const int k = 32 * s + q8 + j;
            const float w30 = W3[k * SD + 0], w31 = W3[k * SD + 1];
            const float w32 = W3[k * SD + 2], w33 = W3[k * SD + 3];
            #pragma unroll
            for (int g = 0; g < 4; ++g) {
                const int n = 64 * g + n0;
                float acc = w30 * Wx[0 * G4 + n] + w31 * Wx[1 * G4 + n] +
                            w32 * Wx[2 * G4 + n] + w33 * Wx[3 * G4 + n];
                wgy[g][s][j] = (_Float16)(acc * gsc[g]);
            }
        }
    // ---- MLP weight frags (wave-split, 16 cols each) ----
    h8 w1f[2], w2f[2], w3f[2];
    #pragma unroll
    for (int s = 0; s < 2; ++s)
        #pragma unroll
        for (int j = 0; j < 8; ++j) {
            const int k = 32 * s + q8 + j;
            w1f[s][j] = (_Float16)W1[k * HID + n0];
            w2f[s][j] = (_Float16)W2[k * HID + n0];
            w3f[s][j] = (_Float16)(col < 4 ? W3[k * SD + col] : 0.0f);
        }
    f4 b1v, b2v, b3v;
    #pragma unroll
    for (int r = 0; r < 4; ++r) {
        b1v[r] = b1[wq + r];
        b2v[r] = b2[wq + r];
        b3v[r] = (quad == 0) ? b3[r] : 0.0f;
    }

    if (tid < 16) {  // out[:,0,:] = 0
        float4 z; z.x = z.y = z.z = z.w = 0.0f;
        *(float4*)(out + (size_t)(row0 + tid) * SEQ * SD) = z;
    }

    _Float16* Hrow = &Hb[col * HST];
    _Float16* Y1row = &Y1b[col * HST];
    _Float16* Y2row = &Y2b[col * HST];
    float* outp = out + ((size_t)(row0 + col) * SEQ + 1) * SD;

    // noise: quad0 lanes own all 8 dims of batch row (row0+col)
    const float* npt = noise + (size_t)(row0 + col) * SEQ * ND;

    const f4 fz = {0.f, 0.f, 0.f, 0.f};
    f4 cst = fz, run = fz;
    f4 zi, zf, zg, zo;

    // nf persists across iterations; only quad0 reloads it. After the prologue,
    // quad1's nf0.x becomes the constant 1.0 feeding the b' bias row (k=8).
    float4 nf0, nf1;
    nf0.x = nf0.y = nf0.z = nf0.w = 0.f;
    nf1 = nf0;

    // ---- prologue: z(0) = noise(0) @ Wxn + b  (h(0)=0, x(0)=0; bias slot 0) ----
    {
        if (quad == 0) { nf0 = *(const float4*)npt; nf1 = *(const float4*)(npt + 4); }
        npt += ND;
        union { h8 v; p2h p[4]; } nb;
        nb.p[0] = __builtin_amdgcn_cvt_pkrtz(nf0.x, nf0.y);
        nb.p[1] = __builtin_amdgcn_cvt_pkrtz(nf0.z, nf0.w);
        nb.p[2] = __builtin_amdgcn_cvt_pkrtz(nf1.x, nf1.y);
        nb.p[3] = __builtin_amdgcn_cvt_pkrtz(nf1.z, nf1.w);
        // transient prologue bias b*gsc (dead after this block)
        #pragma unroll
        for (int g = 0; g < 4; ++g) {
            f4 tb;
            #pragma unroll
            for (int r = 0; r < 4; ++r) tb[r] = b[64 * g + wq + r] * gsc[g];
            f4 z0 = MFMA(wgn[g], nb.v, tb);
            if (g == 0) zi = z0; else if (g == 1) zf = z0;
            else if (g == 2) zg = z0; else zo = z0;
        }
        if (quad == 1) nf0.x = 1.0f;  // enable the b' bias row from step 1 on
    }

    #pragma unroll 1
    for (int t = 0; t < STEPS; ++t) {
        // prefetch noise(t+1) -- consumed at the tail, a full step of latency
        if (quad == 0) { nf0 = *(const float4*)npt; nf1 = *(const float4*)(npt + 4); }
        npt += ND;

        // ---- cell update from complete z(t); 7 trans, exp2-prescaled ----
        f4 hv;
        #pragma unroll
        for (int r = 0; r < 4; ++r) {
            float Ei = EXP2(-fmaxf(zi[r], -15.f * LOG2E));
            float Ef = EXP2(-fmaxf(zf[r], -15.f * LOG2E));
            float Eg = EXP2(-fmaxf(zg[r], -30.f * LOG2E));
            float Eo = EXP2(-zo[r]);
            float Di = 1.f + Ei, Df = 1.f + Ef, Dg = 1.f + Eg, Do = 1.f + Eo;
            float DiDg = Di * Dg;
            float cn = (cst[r] * DiDg + (2.f - Dg) * Df) *
                       __builtin_amdgcn_rcpf(Df * DiDg);
            cst[r] = cn;
            float Ec = EXP2(fmaxf(cn, -15.f) * (-2.f * LOG2E));
            hv[r] = (1.f - Ec) * __builtin_amdgcn_rcpf(Do * (1.f + Ec));
        }
        store4h(Hrow + wq, hv);  // h(t+1)
        __syncthreads();  // B1

        h8 h0 = *(const h8*)(&Hb[col * HST] + q8);
        h8 h1 = *(const h8*)(&Hb[col * HST] + 32 + q8);

        // ---- y1 = relu(h @ W1 + b1) ----
        f4 y1 = MFMA(w1f[0], h0, b1v);
        y1 = MFMA(w1f[1], h1, y1);
        #pragma unroll
        for (int r = 0; r < 4; ++r) y1[r] = fmaxf(y1[r], 0.f);
        store4h(Y1row + wq, y1);

        // pipelined gate-h for z(t+1); C-init = shared zero (bias rides in wgn)
        zi = MFMA(wg[0][0], h0, fz); zi = MFMA(wg[0][1], h1, zi);
        zf = MFMA(wg[1][0], h0, fz); zf = MFMA(wg[1][1], h1, zf);
        zg = MFMA(wg[2][0], h0, fz); zg = MFMA(wg[2][1], h1, zg);
        zo = MFMA(wg[3][0], h0, fz); zo = MFMA(wg[3][1], h1, zo);
        __syncthreads();  // B2

        // ---- y2 = relu(y1 @ W2 + b2) ----
        h8 p0 = *(const h8*)(Y1row + q8);
        h8 p1 = *(const h8*)(Y1row + 32 + q8);
        f4 y2 = MFMA(w2f[0], p0, b2v);
        y2 = MFMA(w2f[1], p1, y2);
        #pragma unroll
        for (int r = 0; r < 4; ++r) y2[r] = fmaxf(y2[r], 0.f);
        store4h(Y2row + wq, y2);
        __syncthreads();  // B3

        h8 q0 = *(const h8*)(Y2row + q8);
        h8 q1 = *(const h8*)(Y2row + 32 + q8);

        // ---- z(t+1) += y2 @ W3W  (the folded x-contribution, on-path) ----
        zi = MFMA(wgy[0][0], q0, zi); zi = MFMA(wgy[0][1], q1, zi);
        zf = MFMA(wgy[1][0], q0, zf); zf = MFMA(wgy[1][1], q1, zf);
        zg = MFMA(wgy[2][0], q0, zg); zg = MFMA(wgy[2][1], q1, zg);
        zo = MFMA(wgy[3][0], q0, zo); zo = MFMA(wgy[3][1], q1, zo);

        // ---- z(t+1) += noise(t+1) @ Wxn + b' (bias row k=8, B=1 via quad1 nf0.x) ----
        union { h8 v; p2h p[4]; } nb;
        nb.p[0] = __builtin_amdgcn_cvt_pkrtz(nf0.x, nf0.y);
        nb.p[1] = __builtin_amdgcn_cvt_pkrtz(nf0.z, nf0.w);
        nb.p[2] = __builtin_amdgcn_cvt_pkrtz(nf1.x, nf1.y);
        nb.p[3] = __builtin_amdgcn_cvt_pkrtz(nf1.z, nf1.w);
        zi = MFMA(wgn[0], nb.v, zi);
        zf = MFMA(wgn[1], nb.v, zf);
        zg = MFMA(wgn[2], nb.v, zg);
        zo = MFMA(wgn[3], nb.v, zo);

        // ---- x(t+1) = y2 @ W3 + b3: output only, wave 0 only, off-path ----
        if (wid == 0) {
            f4 x = MFMA(w3f[0], q0, b3v);
            x = MFMA(w3f[1], q1, x);
            if (quad == 0) {
                run += x;
                *(f4*)outp = run;  // cumsum output, dwordx4
            }
        }
        outp += SD;
    }
}

extern "C" void kernel_launch(void* const* d_in, const int* in_sizes, int n_in,
                              void* d_out, int out_size, void* d_ws, size_t ws_size,
                              hipStream_t stream) {
    genlstm_kernel<<<512, 256, 0, stream>>>(
        (const float*)d_in[0], (const float*)d_in[1], (const float*)d_in[2],
        (const float*)d_in[3], (const float*)d_in[4], (const float*)d_in[5],
        (const float*)d_in[6], (const float*)d_in[7], (const float*)d_in[8],
        (const float*)d_in[9], (float*)d_out);
}

// Round 6
// 364.419 us; speedup vs baseline: 1.4761x; 1.0952x over previous
//
#include <hip/hip_runtime.h>

// GenLSTM: B=8192, T=256 (255 steps), noise=8, seq_dim=4, HID=64, gates=256.
// R11 = R10 + anti-convoy phase skew. R10 post-mortem: scratch gone (WRITE back
// to ~33.5MB output + one-time 26B/thread prologue spill) but dur only -1.5% vs
// R5 => the W3W fold wasn't the stall; wall (3276 cyc/step) ~= VALU-issue
// (1638) + MFMA-issue (852) on SEPARATE pipes => the two co-resident blocks
// (pair = b, b+256 under XCD round-robin: 512 blocks / 8 XCDs / 32 CUs => slot
// 0 = blocks 0..255, slot 1 = 256..511) run phase-CONVOYED: both hit their
// cell-VALU windows together, then their MFMA/LDS windows together. Fix:
// (1) blocks with bit8 set s_sleep ~1664 cyc (half a step) once before the
//     loop -> co-resident pair starts anti-phase (one's cell VALU fills the
//     other's MFMA/barrier/LDS-latency windows);
// (2) s_setprio(1) over the MFMA/LDS phase (B1..tail), 0 over the cell phase:
//     asymmetric arbitration keeps the pair from re-converging.
// Kept from R10: R5 skeleton (512x256, M=16, 3 barriers, 2 blocks/CU), W3W fold
// (z += y2@W3W after B3; x off-path, wave0 only), register noise B-frag
// prefetched a full step, bias b' folded into wgn row k=8 (B=1 via quad1 nf0.x),
// exp2-prescaled gates, 7-trans cell, prologue bias via transient loads.

typedef _Float16 h8 __attribute__((ext_vector_type(8)));
typedef __fp16 p2h __attribute__((ext_vector_type(2)));
typedef float f4 __attribute__((ext_vector_type(4)));

#define MFMA(a, b, c) __builtin_amdgcn_mfma_f32_16x16x32_f16(a, b, c, 0, 0, 0)
#define EXP2(x) __builtin_amdgcn_exp2f(x)

constexpr int SEQ = 256, STEPS = 255, ND = 8, SD = 4, HID = 64, G4 = 256;
constexpr int HST = 72;  // h/y row stride (f16): 16B-aligned rows
constexpr float LOG2E = 1.44269504f;

__device__ __forceinline__ void store4h(_Float16* p, f4 v) {
    p2h lo = __builtin_amdgcn_cvt_pkrtz(v[0], v[1]);
    p2h hi = __builtin_amdgcn_cvt_pkrtz(v[2], v[3]);
    float2 st;
    st.x = __builtin_bit_cast(float, lo);
    st.y = __builtin_bit_cast(float, hi);
    *(float2*)p = st;
}

__global__ __launch_bounds__(256, 2) void genlstm_kernel(
    const float* __restrict__ noise, const float* __restrict__ Wx,
    const float* __restrict__ Wh, const float* __restrict__ b,
    const float* __restrict__ W1, const float* __restrict__ b1,
    const float* __restrict__ W2, const float* __restrict__ b2,
    const float* __restrict__ W3, const float* __restrict__ b3,
    float* __restrict__ out)
{
    __shared__ alignas(16) _Float16 Hb[16 * HST];
    __shared__ alignas(16) _Float16 Y1b[16 * HST];
    __shared__ alignas(16) _Float16 Y2b[16 * HST];

    const int tid = threadIdx.x, wid = tid >> 6, lane = tid & 63;
    const int col = lane & 15, quad = lane >> 4, q8 = quad * 8;
    const int row0 = blockIdx.x * 16;
    const int n0 = wid * 16 + col;       // gate/hid col for weight frags
    const int wq = wid * 16 + quad * 4;  // C^T write col base

    const float gsc[4] = {LOG2E, LOG2E, 2.f * LOG2E, LOG2E};  // i,f,g,o

    // ---- gate weight frags: Wh slices (k=0..63), exp2-prescaled ----
    h8 wg[4][2];
    #pragma unroll
    for (int g = 0; g < 4; ++g)
        #pragma unroll
        for (int s = 0; s < 2; ++s)
            #pragma unroll
            for (int j = 0; j < 8; ++j)
                wg[g][s][j] = (_Float16)(Wh[(32 * s + q8 + j) * G4 + 64 * g + n0] * gsc[g]);

    // ---- noise+bias slice: k=0..7 -> Wxn rows (quad0), k=8 -> b' row (quad1 j=0) ----
    // b' = b + b3 @ Wx_x  (the x-fold bias), prescaled.
    h8 wgn[4];
    #pragma unroll
    for (int g = 0; g < 4; ++g)
        #pragma unroll
        for (int j = 0; j < 8; ++j) {
            const int k = q8 + j;
            const int n = 64 * g + n0;
            float v = 0.0f;
            if (k < 8) v = Wx[(4 + k) * G4 + n];
            else if (k == 8) {
                float bx = b3[0] * Wx[0 * G4 + n] + b3[1] * Wx[1 * G4 + n] +
                           b3[2] * Wx[2 * G4 + n] + b3[3] * Wx[3 * G4 + n];
                v = b[n] + bx;
            }
            wgn[g][j] = (_Float16)(v * gsc[g]);
        }

    // ---- W3W = W3 @ Wx[0:4,:] fold (prescaled): z += y2 @ W3W ----
    h8 wgy[4][2];
    #pragma unroll
    for (int s = 0; s < 2; ++s)
        #pragma unroll
        for (int j = 0; j < 8; ++j) {
            const int k = 32 * s + q8 + j;
            const float w30 = W3[k * SD + 0], w31 = W3[k * SD + 1];
            const float w32 = W3[k * SD + 2], w33 = W3[k * SD + 3];
            #pragma unroll
            for (int g = 0; g < 4; ++g) {
                const int n = 64 * g + n0;
                float acc = w30 * Wx[0 * G4 + n] + w31 * Wx[1 * G4 + n] +
                            w32 * Wx[2 * G4 + n] + w33 * Wx[3 * G4 + n];
                wgy[g][s][j] = (_Float16)(acc * gsc[g]);
            }
        }
    // ---- MLP weight frags (wave-split, 16 cols each) ----
    h8 w1f[2], w2f[2], w3f[2];
    #pragma unroll
    for (int s = 0; s < 2; ++s)
        #pragma unroll
        for (int j = 0; j < 8; ++j) {
            const int k = 32 * s + q8 + j;
            w1f[s][j] = (_Float16)W1[k * HID + n0];
            w2f[s][j] = (_Float16)W2[k * HID + n0];
            w3f[s][j] = (_Float16)(col < 4 ? W3[k * SD + col] : 0.0f);
        }
    f4 b1v, b2v, b3v;
    #pragma unroll
    for (int r = 0; r < 4; ++r) {
        b1v[r] = b1[wq + r];
        b2v[r] = b2[wq + r];
        b3v[r] = (quad == 0) ? b3[r] : 0.0f;
    }

    if (tid < 16) {  // out[:,0,:] = 0
        float4 z; z.x = z.y = z.z = z.w = 0.0f;
        *(float4*)(out + (size_t)(row0 + tid) * SEQ * SD) = z;
    }

    _Float16* Hrow = &Hb[col * HST];
    _Float16* Y1row = &Y1b[col * HST];
    _Float16* Y2row = &Y2b[col * HST];
    float* outp = out + ((size_t)(row0 + col) * SEQ + 1) * SD;

    // noise: quad0 lanes own all 8 dims of batch row (row0+col)
    const float* npt = noise + (size_t)(row0 + col) * SEQ * ND;

    const f4 fz = {0.f, 0.f, 0.f, 0.f};
    f4 cst = fz, run = fz;
    f4 zi, zf, zg, zo;

    // nf persists across iterations; only quad0 reloads it. After the prologue,
    // quad1's nf0.x becomes the constant 1.0 feeding the b' bias row (k=8).
    float4 nf0, nf1;
    nf0.x = nf0.y = nf0.z = nf0.w = 0.f;
    nf1 = nf0;

    // ---- anti-convoy skew: co-resident pair = (b, b+256) under XCD
    // round-robin dispatch; shift slot-1 blocks by ~half a step (26*64 cyc)
    // so the pair runs anti-phase (cell-VALU vs MFMA/LDS windows). Wrong
    // pairing guess costs 0.7us once and nothing else. ----
    if (blockIdx.x & 256) __builtin_amdgcn_s_sleep(26);

    // ---- prologue: z(0) = noise(0) @ Wxn + b  (h(0)=0, x(0)=0; bias slot 0) ----
    {
        if (quad == 0) { nf0 = *(const float4*)npt; nf1 = *(const float4*)(npt + 4); }
        npt += ND;
        union { h8 v; p2h p[4]; } nb;
        nb.p[0] = __builtin_amdgcn_cvt_pkrtz(nf0.x, nf0.y);
        nb.p[1] = __builtin_amdgcn_cvt_pkrtz(nf0.z, nf0.w);
        nb.p[2] = __builtin_amdgcn_cvt_pkrtz(nf1.x, nf1.y);
        nb.p[3] = __builtin_amdgcn_cvt_pkrtz(nf1.z, nf1.w);
        // transient prologue bias b*gsc (dead after this block)
        #pragma unroll
        for (int g = 0; g < 4; ++g) {
            f4 tb;
            #pragma unroll
            for (int r = 0; r < 4; ++r) tb[r] = b[64 * g + wq + r] * gsc[g];
            f4 z0 = MFMA(wgn[g], nb.v, tb);
            if (g == 0) zi = z0; else if (g == 1) zf = z0;
            else if (g == 2) zg = z0; else zo = z0;
        }
        if (quad == 1) nf0.x = 1.0f;  // enable the b' bias row from step 1 on
    }

    #pragma unroll 1
    for (int t = 0; t < STEPS; ++t) {
        // prefetch noise(t+1) -- consumed at the tail, a full step of latency
        if (quad == 0) { nf0 = *(const float4*)npt; nf1 = *(const float4*)(npt + 4); }
        npt += ND;

        // ---- cell update from complete z(t); 7 trans, exp2-prescaled ----
        // (prio 0: this is the VALU phase the other block's MFMA overlaps)
        f4 hv;
        #pragma unroll
        for (int r = 0; r < 4; ++r) {
            float Ei = EXP2(-fmaxf(zi[r], -15.f * LOG2E));
            float Ef = EXP2(-fmaxf(zf[r], -15.f * LOG2E));
            float Eg = EXP2(-fmaxf(zg[r], -30.f * LOG2E));
            float Eo = EXP2(-zo[r]);
            float Di = 1.f + Ei, Df = 1.f + Ef, Dg = 1.f + Eg, Do = 1.f + Eo;
            float DiDg = Di * Dg;
            float cn = (cst[r] * DiDg + (2.f - Dg) * Df) *
                       __builtin_amdgcn_rcpf(Df * DiDg);
            cst[r] = cn;
            float Ec = EXP2(fmaxf(cn, -15.f) * (-2.f * LOG2E));
            hv[r] = (1.f - Ec) * __builtin_amdgcn_rcpf(Do * (1.f + Ec));
        }
        store4h(Hrow + wq, hv);  // h(t+1)
        __syncthreads();  // B1

        __builtin_amdgcn_s_setprio(1);  // MFMA/LDS phase begins

        h8 h0 = *(const h8*)(&Hb[col * HST] + q8);
        h8 h1 = *(const h8*)(&Hb[col * HST] + 32 + q8);

        // ---- y1 = relu(h @ W1 + b1) ----
        f4 y1 = MFMA(w1f[0], h0, b1v);
        y1 = MFMA(w1f[1], h1, y1);
        #pragma unroll
        for (int r = 0; r < 4; ++r) y1[r] = fmaxf(y1[r], 0.f);
        store4h(Y1row + wq, y1);

        // pipelined gate-h for z(t+1); C-init = shared zero (bias rides in wgn)
        zi = MFMA(wg[0][0], h0, fz); zi = MFMA(wg[0][1], h1, zi);
        zf = MFMA(wg[1][0], h0, fz); zf = MFMA(wg[1][1], h1, zf);
        zg = MFMA(wg[2][0], h0, fz); zg = MFMA(wg[2][1], h1, zg);
        zo = MFMA(wg[3][0], h0, fz); zo = MFMA(wg[3][1], h1, zo);
        __syncthreads();  // B2

        // ---- y2 = relu(y1 @ W2 + b2) ----
        h8 p0 = *(const h8*)(Y1row + q8);
        h8 p1 = *(const h8*)(Y1row + 32 + q8);
        f4 y2 = MFMA(w2f[0], p0, b2v);
        y2 = MFMA(w2f[1], p1, y2);
        #pragma unroll
        for (int r = 0; r < 4; ++r) y2[r] = fmaxf(y2[r], 0.f);
        store4h(Y2row + wq, y2);
        __syncthreads();  // B3

        h8 q0 = *(const h8*)(Y2row + q8);
        h8 q1 = *(const h8*)(Y2row + 32 + q8);

        // ---- z(t+1) += y2 @ W3W  (the folded x-contribution, on-path) ----
        zi = MFMA(wgy[0][0], q0, zi); zi = MFMA(wgy[0][1], q1, zi);
        zf = MFMA(wgy[1][0], q0, zf); zf = MFMA(wgy[1][1], q1, zf);
        zg = MFMA(wgy[2][0], q0, zg); zg = MFMA(wgy[2][1], q1, zg);
        zo = MFMA(wgy[3][0], q0, zo); zo = MFMA(wgy[3][1], q1, zo);

        // ---- z(t+1) += noise(t+1) @ Wxn + b' (bias row k=8, B=1 via quad1 nf0.x) ----
        union { h8 v; p2h p[4]; } nb;
        nb.p[0] = __builtin_amdgcn_cvt_pkrtz(nf0.x, nf0.y);
        nb.p[1] = __builtin_amdgcn_cvt_pkrtz(nf0.z, nf0.w);
        nb.p[2] = __builtin_amdgcn_cvt_pkrtz(nf1.x, nf1.y);
        nb.p[3] = __builtin_amdgcn_cvt_pkrtz(nf1.z, nf1.w);
        zi = MFMA(wgn[0], nb.v, zi);
        zf = MFMA(wgn[1], nb.v, zf);
        zg = MFMA(wgn[2], nb.v, zg);
        zo = MFMA(wgn[3], nb.v, zo);

        // ---- x(t+1) = y2 @ W3 + b3: output only, wave 0 only, off-path ----
        if (wid == 0) {
            f4 x = MFMA(w3f[0], q0, b3v);
            x = MFMA(w3f[1], q1, x);
            if (quad == 0) {
                run += x;
                *(f4*)outp = run;  // cumsum output, dwordx4
            }
        }
        outp += SD;

        __builtin_amdgcn_s_setprio(0);  // back to VALU phase (cell of t+1)
    }
}

extern "C" void kernel_launch(void* const* d_in, const int* in_sizes, int n_in,
                              void* d_out, int out_size, void* d_ws, size_t ws_size,
                              hipStream_t stream) {
    genlstm_kernel<<<512, 256, 0, stream>>>(
        (const float*)d_in[0], (const float*)d_in[1], (const float*)d_in[2],
        (const float*)d_in[3], (const float*)d_in[4], (const float*)d_in[5],
        (const float*)d_in[6], (const float*)d_in[7], (const float*)d_in[8],
        (const float*)d_in[9], (float*)d_out);
}